// Round 1
// 82.867 us; speedup vs baseline: 1.1578x; 1.1578x over previous
//
#include <hip/hip_runtime.h>
#include <math.h>

// Gabor atom renderer — round 5: fully fused single launch, zero workspace.
//
// out[t] = sum_n a_n * exp(-tc^2/(2 sg^2+1e-8)) * cos(2pi(om tc + 0.5 gm tc^2)+ph)
//          |tc| <= 4 sg,  tc = t/SR - tau_n
//
// vs round 4 (2-launch prep+render, ws lists, atomics):
//  - ONE kernel, ONE block per 512-sample tile (141 blocks x 512 threads)
//  - each block ballot-compacts its own atom list straight into LDS
//    (8 chunk iterations over N=4096; cross-wave ordered via LDS prefix)
//  - derived params (k, 0.5*gm, ph/2pi) staged once in LDS
//  - one sample per thread, plain coalesced store: no atomics, no out-zeroing,
//    no counts/lists global round-trip, NO d_ws USE AT ALL (removes the
//    stream-ordered dependency on the harness's 256 MiB workspace poison fill)
//  - numerics per (atom,sample) pair identical to round 4 (exp2/fract/v_cos)

#define SR      24000.0f
#define TWO_PI  6.2831853071795864769f
#define LOG2E   1.4426950408889634f

#define TS      512            // samples per tile == threads per block
#define BLK     512
#define NWAVES  (BLK / 64)
#define MAXA    512            // max atoms listed per tile (mean ~157 at TS=512)

__global__ __launch_bounds__(BLK) void gabor_fused_kernel(
        const float* __restrict__ amp,
        const float* __restrict__ tau,
        const float* __restrict__ omega,
        const float* __restrict__ sigma,
        const float* __restrict__ phi,
        const float* __restrict__ gamma,
        float*       __restrict__ out,
        int N, int T) {
    __shared__ int    s_list[MAXA];
    __shared__ int    s_wcnt[NWAVES];
    __shared__ float4 s_p4[MAXA];   // a, om, 0.5*gm, k
    __shared__ float2 s_p2[MAXA];   // tau, ph/(2pi)

    const int tile = blockIdx.x;
    const int tid  = threadIdx.x;
    const int wid  = tid >> 6;
    const int lane = tid & 63;

    // ---------------- phase 1: bin atoms overlapping this tile -------------
    // ordered ballot compaction across all 8 waves (deterministic, ascending)
    const float tstart = (float)(tile * TS) * (1.0f / SR);
    const float tend   = (float)(tile * TS + TS - 1) * (1.0f / SR);
    const float slack  = 2.0f / SR;

    int total = 0;
    for (int c = 0; c < N; c += BLK) {
        const int ai = c + tid;
        bool hit = false;
        if (ai < N) {
            const float tu = tau[ai];
            const float w  = 4.0f * sigma[ai] + slack;
            hit = ((tu - w) <= tend) && ((tu + w) >= tstart);
        }
        const unsigned long long m = __ballot(hit);
        if (lane == 0) s_wcnt[wid] = (int)__popcll(m);
        __syncthreads();

        int off = total;               // offset of this wave's hits
        #pragma unroll
        for (int w2 = 0; w2 < NWAVES; ++w2) {
            const int c2 = s_wcnt[w2]; // broadcast LDS read
            if (w2 < wid) off += c2;
            total += c2;               // running block-wide total
        }
        if (hit) {
            const int pos = off + (int)__popcll(m & ((1ull << lane) - 1ull));
            if (pos < MAXA) s_list[pos] = ai;
        }
        __syncthreads();               // protect s_wcnt reuse next iteration
    }
    const int cnt = (total < MAXA) ? total : MAXA;

    // ---------------- phase 2: stage derived params in LDS -----------------
    // cnt <= MAXA <= BLK: single pass
    if (tid < cnt) {
        const int idx = s_list[tid];
        const float a  = amp[idx];
        const float tu = tau[idx];
        const float om = omega[idx];
        const float sg = sigma[idx];
        const float ph = phi[idx];
        const float gm = gamma[idx];
        const float k  = -LOG2E / (2.0f * sg * sg + 1e-8f);
        s_p4[tid] = make_float4(a, om, 0.5f * gm, k);
        s_p2[tid] = make_float2(tu, ph * (1.0f / TWO_PI));
    }
    __syncthreads();

    // ---------------- phase 3: render, one sample per thread ---------------
    const int   t_idx = tile * TS + tid;
    const float t0    = (float)t_idx * (1.0f / SR);
    float acc = 0.0f;
    #pragma unroll 4
    for (int i = 0; i < cnt; ++i) {
        const float4 p4 = s_p4[i];     // uniform-address broadcast reads
        const float2 p2 = s_p2[i];
        const float tc  = t0 - p2.x;
        const float tc2 = tc * tc;
        const float env = exp2f(p4.w * tc2);                  // v_exp_f32
        const float rev = fmaf(p4.y, tc, fmaf(p4.z, tc2, p2.y));
        const float r   = rev - floorf(rev);                  // v_fract
        const float c   = __builtin_amdgcn_cosf(r);           // v_cos_f32 (rev)
        acc = fmaf(p4.x * env, c, acc);
    }
    if (t_idx < T) out[t_idx] = acc;   // exactly one coalesced store per sample
}

extern "C" void kernel_launch(void* const* d_in, const int* in_sizes, int n_in,
                              void* d_out, int out_size, void* d_ws, size_t ws_size,
                              hipStream_t stream) {
    const float* amp   = (const float*)d_in[0];
    const float* tau   = (const float*)d_in[1];
    const float* omega = (const float*)d_in[2];
    const float* sigma = (const float*)d_in[3];
    const float* phi   = (const float*)d_in[4];
    const float* gamma = (const float*)d_in[5];

    float* out = (float*)d_out;
    const int T = out_size;                 // 72000
    const int N = in_sizes[0];              // 4096
    const int ntiles = (T + TS - 1) / TS;   // 141

    (void)d_ws; (void)ws_size;              // workspace intentionally unused

    gabor_fused_kernel<<<ntiles, BLK, 0, stream>>>(amp, tau, omega, sigma, phi,
                                                   gamma, out, N, T);
}